// Round 1
// baseline (66.487 us; speedup 1.0000x reference)
//
#include <hip/hip_runtime.h>
#include <hip/hip_bf16.h>

// CRPS ensemble loss:
//   term1 = mean_i |s_i - y|            (per pixel)
//   term2 = 0.5 * mean_{i,j} |s_i - s_j| = (1/N^2) * sum_{i<j} |s_i - s_j|
//   out   = mean_p (term1 - term2)
// N = 16 samples, P = B*C*H*W pixels. All fp32.
// Strategy: one thread per float4 pixel-group; all 16 samples cached in
// registers; O(N^2) pair sum in-register (never materialize the [N,N,...]
// tensor the reference builds). Block partials -> d_ws, tiny finish kernel.

#define NS 16

__global__ __launch_bounds__(256) void crps_partial(
    const float* __restrict__ samples,
    const float* __restrict__ target,
    float* __restrict__ partials,
    int P /* pixels, divisible by 4 */) {

    const int tid = blockIdx.x * blockDim.x + threadIdx.x;  // float4-group index
    const int P4 = P >> 2;

    float local = 0.0f;
    if (tid < P4) {
        const float4 y4 = reinterpret_cast<const float4*>(target)[tid];
        const float yv[4] = {y4.x, y4.y, y4.z, y4.w};

        float s[NS][4];
#pragma unroll
        for (int i = 0; i < NS; ++i) {
            const float4 v =
                reinterpret_cast<const float4*>(samples + (size_t)i * P)[tid];
            s[i][0] = v.x; s[i][1] = v.y; s[i][2] = v.z; s[i][3] = v.w;
        }

#pragma unroll
        for (int c = 0; c < 4; ++c) {
            float sum1 = 0.0f;  // sum_i |s_i - y|
            float sum2 = 0.0f;  // sum_{i<j} |s_i - s_j|
#pragma unroll
            for (int i = 0; i < NS; ++i) {
                sum1 += fabsf(s[i][c] - yv[c]);
#pragma unroll
                for (int j = i + 1; j < NS; ++j) {
                    sum2 += fabsf(s[i][c] - s[j][c]);
                }
            }
            // term1 - term2 = sum1/N - sum2/N^2
            local += sum1 * (1.0f / (float)NS)
                   - sum2 * (1.0f / (float)(NS * NS));
        }
    }

    // wave(64) shuffle reduction
#pragma unroll
    for (int off = 32; off > 0; off >>= 1)
        local += __shfl_down(local, off, 64);

    __shared__ float wsum[4];  // 256 threads = 4 waves
    const int lane = threadIdx.x & 63;
    const int wid  = threadIdx.x >> 6;
    if (lane == 0) wsum[wid] = local;
    __syncthreads();
    if (threadIdx.x == 0)
        partials[blockIdx.x] = wsum[0] + wsum[1] + wsum[2] + wsum[3];
}

__global__ __launch_bounds__(256) void crps_finish(
    const float* __restrict__ partials,
    float* __restrict__ out,
    int nblocks, float scale) {

    float local = 0.0f;
    for (int i = threadIdx.x; i < nblocks; i += 256)
        local += partials[i];

#pragma unroll
    for (int off = 32; off > 0; off >>= 1)
        local += __shfl_down(local, off, 64);

    __shared__ float wsum[4];
    const int lane = threadIdx.x & 63;
    const int wid  = threadIdx.x >> 6;
    if (lane == 0) wsum[wid] = local;
    __syncthreads();
    if (threadIdx.x == 0)
        out[0] = (wsum[0] + wsum[1] + wsum[2] + wsum[3]) * scale;
}

extern "C" void kernel_launch(void* const* d_in, const int* in_sizes, int n_in,
                              void* d_out, int out_size, void* d_ws, size_t ws_size,
                              hipStream_t stream) {
    const float* samples = (const float*)d_in[0];  // [N, P]
    const float* target  = (const float*)d_in[1];  // [P]
    float* out = (float*)d_out;
    float* partials = (float*)d_ws;

    const int P  = in_sizes[1];          // 262144
    const int P4 = P >> 2;               // 65536
    const int threads = 256;
    const int blocks  = (P4 + threads - 1) / threads;  // 256

    crps_partial<<<blocks, threads, 0, stream>>>(samples, target, partials, P);
    crps_finish<<<1, threads, 0, stream>>>(partials, out, blocks, 1.0f / (float)P);
}